// Round 12
// baseline (202.650 us; speedup 1.0000x reference)
//
#include <hip/hip_runtime.h>
#include <stdint.h>

typedef unsigned short u16;
typedef __bf16 bf16x8 __attribute__((ext_vector_type(8)));
typedef u16 u16x8 __attribute__((ext_vector_type(8)));
typedef u16 u16x4 __attribute__((ext_vector_type(4)));
typedef float f32x4 __attribute__((ext_vector_type(4)));
typedef float f32x16 __attribute__((ext_vector_type(16)));

#define SEQ 4096
#define CD 1024
#define NH 16
#define DHD 64

__device__ __forceinline__ u16 f2bf(float f) {
  union { float f; unsigned u; } v; v.f = f;
  unsigned r = v.u + 0x7fffu + ((v.u >> 16) & 1u);
  return (u16)(r >> 16);
}
__device__ __forceinline__ unsigned fbits(float f) {
  union { float f; unsigned u; } v; v.f = f; return v.u;
}
__device__ __forceinline__ float fexp2(float x) {
#if __has_builtin(__builtin_amdgcn_exp2f)
  return __builtin_amdgcn_exp2f(x);
#else
  return exp2f(x);
#endif
}

__device__ __forceinline__ void load_lds16(const u16* g, u16* l) {
  __builtin_amdgcn_global_load_lds((const __attribute__((address_space(1))) void*)g,
                                   (__attribute__((address_space(3))) void*)l, 16, 0, 0);
}

// ---------------- convert fp32 -> bf16 (single dispatch) ----------------
__global__ __launch_bounds__(256) void cvt_all(const float* __restrict__ x, const float* __restrict__ Wq,
                                               const float* __restrict__ Wk, const float* __restrict__ Wv,
                                               const float* __restrict__ Wp,
                                               u16* __restrict__ xb, u16* __restrict__ Wb, u16* __restrict__ Wpb) {
  int b = blockIdx.x;
  const float* src; u16* dst; int base;
  if (b < 2048)      { src = x;  dst = xb;             base = b; }
  else if (b < 2560) { src = Wq; dst = Wb;             base = b - 2048; }
  else if (b < 3072) { src = Wk; dst = Wb + CD * CD;   base = b - 2560; }
  else if (b < 3584) { src = Wv; dst = Wb + 2*CD*CD;   base = b - 3072; }
  else               { src = Wp; dst = Wpb;            base = b - 3584; }
  int i = (base * 256 + (int)threadIdx.x) * 8;
  float4 a = *(const float4*)(src + i);
  float4 c = *(const float4*)(src + i + 4);
  u16x8 o;
  o[0] = f2bf(a.x); o[1] = f2bf(a.y); o[2] = f2bf(a.z); o[3] = f2bf(a.w);
  o[4] = f2bf(c.x); o[5] = f2bf(c.y); o[6] = f2bf(c.z); o[7] = f2bf(c.w);
  *(u16x8*)(dst + i) = o;
}

// ---------------- GEMM: out = (A * Bw^T + bias) * oscale ----------------
// ROUND-2 VERSION — proven best across 4 falsified alternatives (BN=64, BM=64,
// BK=64+swizzle, LDS dbuf: all +9-15us). This 128x128/BK=32 structure at K=1024
// is its own ceiling; next lever would be a 256^2 8-phase rewrite.
// MODE 0: bf16 row-major; MODE 1: bf16 transposed [1024,4096]; MODE 2: f32 row-major
template<int MODE>
__device__ __forceinline__ void gemm_core(const u16* __restrict__ A, const u16* __restrict__ Bw,
                                          const float* __restrict__ bias, void* __restrict__ outp,
                                          float oscale) {
  constexpr int K = CD, N = CD;
  __shared__ u16 As[128 * 32];
  __shared__ u16 Bs[128 * 32];
  const int tid = threadIdx.x;
  const int w = tid >> 6, L = tid & 63, q = L >> 4, ln = L & 15;
  const int rowA0 = blockIdx.y * 128, rowB0 = blockIdx.x * 128;
  const int wr = (w >> 1) * 64, wc = (w & 1) * 64;
  f32x4 acc[4][4] = {};
  for (int k0 = 0; k0 < K; k0 += 32) {
#pragma unroll
    for (int pass = 0; pass < 2; ++pass) {
      int off = pass * 4096 + tid * 16;
      int row = off >> 6;
      int cole = (off & 63) >> 1;
      load_lds16(A + (size_t)(rowA0 + row) * K + k0 + cole, As + pass * 2048 + w * 512);
      load_lds16(Bw + (size_t)(rowB0 + row) * K + k0 + cole, Bs + pass * 2048 + w * 512);
    }
    __syncthreads();
    bf16x8 af[4], bg[4];
#pragma unroll
    for (int i = 0; i < 4; ++i) af[i] = *(const bf16x8*)(As + (wr + i * 16 + ln) * 32 + q * 8);
#pragma unroll
    for (int i = 0; i < 4; ++i) bg[i] = *(const bf16x8*)(Bs + (wc + i * 16 + ln) * 32 + q * 8);
#pragma unroll
    for (int i = 0; i < 4; ++i)
#pragma unroll
      for (int j = 0; j < 4; ++j)
        acc[i][j] = __builtin_amdgcn_mfma_f32_16x16x32_bf16(af[i], bg[j], acc[i][j], 0, 0, 0);
    __syncthreads();
  }
#pragma unroll
  for (int i = 0; i < 4; ++i) {
#pragma unroll
    for (int j = 0; j < 4; ++j) {
      int col = rowB0 + wc + j * 16 + ln;
      float bb = bias[col];
#pragma unroll
      for (int r = 0; r < 4; ++r) {
        int row = rowA0 + wr + i * 16 + q * 4 + r;
        float v = (acc[i][j][r] + bb) * oscale;
        if (MODE == 0)      ((u16*)outp)[(size_t)row * N + col] = f2bf(v);
        else if (MODE == 1) ((u16*)outp)[(size_t)col * SEQ + row] = f2bf(v);
        else                ((float*)outp)[(size_t)row * N + col] = v;
      }
    }
  }
}

__global__ __launch_bounds__(256) void gemm_qkv(const u16* __restrict__ A, const u16* __restrict__ W3,
                                                const float* __restrict__ bq, const float* __restrict__ bk,
                                                const float* __restrict__ bv, u16* __restrict__ Qb,
                                                u16* __restrict__ Kb, u16* __restrict__ VTb) {
  int z = blockIdx.z;
  // Q scale = C^-0.5 * log2(e): softmax scale AND exp->exp2 conversion folded into Q
  if (z == 0)      gemm_core<0>(A, W3,               bq, Qb,  0.0450842200f);
  else if (z == 1) gemm_core<0>(A, W3 + CD * CD,     bk, Kb,  1.0f);
  else             gemm_core<1>(A, W3 + 2 * CD * CD, bv, VTb, 1.0f);      // V stored transposed
}

__global__ __launch_bounds__(256) void gemm_proj(const u16* __restrict__ A, const u16* __restrict__ Bw,
                                                 const float* __restrict__ bias, float* __restrict__ out) {
  gemm_core<2>(A, Bw, bias, out, 1.0f);
}

// ---------------- flash attention (causal), 64 q-rows/block, 4 waves, in-block key-split ----------------
// FINAL (round-9 configuration, best measured 200.8us total / attn 62.0us).
// Session-verified constraints on this body:
//  - (256,3) bound FINAL: true live set ~144 regs incl. AGPR acc — any 128-reg cap spills (R1/R8).
//  - V staging in LDS is load-bearing: per-lane SEQ-strided V-from-global regressed 26us (R4).
//  - Latency-bound & TLP-masked (R10: 2 blk/CU = 86% time for 50% work); occupancy is the only
//    lever that ever moved it and registers cap it at 3 blk/CU.
//  - End-barrier vmcnt drain is NOT the stall (R11 null); the intra-wave serial
//    QK(4-chained MFMA) -> exp2/pack -> PV(4-chained MFMA) chain is.
//  - Balanced per-CU qt map (R9, -3us): every CU's four blocks sum to 126 work units.
// Q pre-scaled by C^-0.5*log2(e) -> native exp2. No running max (|S'|<~2.2, l linear).
// 4 waves = 2 pairs: pair p owns key-tile range [p?nt0:0, p?qt+1:nt0), nt0=ceil((qt+1)/2).
__global__ __launch_bounds__(256, 3) void attn_kernel(const u16* __restrict__ Q, const u16* __restrict__ Kg,
                                                      const u16* __restrict__ VTg, u16* __restrict__ O) {
  __shared__ u16 Ks[2][64 * 72];   // [pair]
  __shared__ u16 Vt[2][64 * 72];
  const int tid = threadIdx.x, w = tid >> 6, L = tid & 63;
  const int ln = L & 31, hh = L >> 5;
  const int p = w >> 1, sub = w & 1;         // pair = key-half, sub = q-subtile
  const int b = blockIdx.x;
  // balanced block->qt map (see header comment)
  const int t4 = (b >> 4) & 15, kq = b >> 8;
  const int qt = (kq == 0) ? t4 : (kq == 1) ? 63 - t4 : (kq == 2) ? 31 - t4 : 32 + t4;
  const int h = b & 15;
  const int colH = h * DHD;
  const int qrow0 = qt * 64 + sub * 32;
  const int nt0 = (qt + 2) >> 1;             // pair0 tiles [0,nt0), pair1 [nt0, qt+1)
  int jt = p ? nt0 : 0;
  const int jt_end = p ? (qt + 1) : nt0;
  // Q B-frags (k = kk*16 + hh*8 + j over d=0..63), hoisted
  bf16x8 qf[4];
#pragma unroll
  for (int kk = 0; kk < 4; ++kk)
    qf[kk] = *(const bf16x8*)(Q + (size_t)(qrow0 + ln) * CD + colH + kk * 16 + hh * 8);
  f32x16 oa[2] = {};
  f32x4 lsv = {};                            // 4-way split lsum: breaks the 32-deep dependent add chain
  // staging map (pair-local 128 threads): c-th chunk -> row c*16 + (ptid>>3), x = ptid&7
  const int ptid = tid & 127;
  const int srow = ptid >> 3, sx = ptid & 7;
  u16* KsP = Ks[p];
  u16* VtP = Vt[p];
  u16x8 kr[4], vr[4];
  bool active = jt < jt_end;                 // pair1 empty only when qt==0
  if (active) {
#pragma unroll
    for (int c = 0; c < 4; ++c) {
      kr[c] = *(const u16x8*)(Kg + (size_t)(jt * 64 + c * 16 + srow) * CD + colH + sx * 8);
      vr[c] = *(const u16x8*)(VTg + (size_t)(colH + c * 16 + srow) * SEQ + jt * 64 + sx * 8);
    }
  }
  for (int i = 0; i < nt0; ++i) {            // nt0 is block-uniform -> barriers are safe
    if (active) {
#pragma unroll
      for (int c = 0; c < 4; ++c) {
        *(u16x8*)(KsP + (c * 16 + srow) * 72 + sx * 8) = kr[c];
        *(u16x8*)(VtP + (c * 16 + srow) * 72 + sx * 8) = vr[c];
      }
    }
    __syncthreads();
    const bool hasnext = (jt + 1) < jt_end;
    if (hasnext) {                           // prefetch next tile; latency hidden behind compute
      const size_t kb2 = (size_t)(jt + 1) * 64;
#pragma unroll
      for (int c = 0; c < 4; ++c) {
        kr[c] = *(const u16x8*)(Kg + (kb2 + c * 16 + srow) * CD + colH + sx * 8);
        vr[c] = *(const u16x8*)(VTg + (size_t)(colH + c * 16 + srow) * SEQ + kb2 + sx * 8);
      }
    }
    if (active) {
      const bool diag = (jt == qt);
      // ---- per nt-half: S^T = K Q^T, mask, exp2, pack, swap, PV — pk live only 8 regs ----
#pragma unroll
      for (int nt = 0; nt < 2; ++nt) {
        f32x16 a = {};
        __builtin_amdgcn_s_setprio(1);
#pragma unroll
        for (int kk = 0; kk < 4; ++kk) {
          bf16x8 kf = *(const bf16x8*)(KsP + (nt * 32 + ln) * 72 + kk * 16 + hh * 8);
          a = __builtin_amdgcn_mfma_f32_32x32x16_bf16(kf, qf[kk], a, 0, 0, 0);
        }
        __builtin_amdgcn_s_setprio(0);
#pragma unroll
        for (int r = 0; r < 16; ++r) {
          float sv = a[r];
          if (diag) {
            const int key_l = nt * 32 + (r & 3) + 8 * (r >> 2) + 4 * hh;
            if (key_l > sub * 32 + ln) sv = -1e30f;
          }
          float pe = fexp2(sv);
          lsv[r & 3] += pe;
          a[r] = pe;
        }
        // pack fp32 pairs -> bf16 (truncation): pk holds keys (2i, 2i+1) of this lane's set
        unsigned pk[8];
#pragma unroll
        for (int i2 = 0; i2 < 8; ++i2)
          pk[i2] = __builtin_amdgcn_perm(fbits(a[2 * i2 + 1]), fbits(a[2 * i2]), 0x07060302);
        // exchange complementary key quads across half-wave: builds PV B-frags in-place
#pragma unroll
        for (int b0 = 0; b0 < 8; b0 += 4) {
          asm("v_permlane32_swap_b32 %0, %1" : "+v"(pk[b0 + 0]), "+v"(pk[b0 + 2]));
          asm("v_permlane32_swap_b32 %0, %1" : "+v"(pk[b0 + 1]), "+v"(pk[b0 + 3]));
        }
        // O^T += V^T P^T for this nt-half's two key-slices (s = nt*2 + s2)
        __builtin_amdgcn_s_setprio(1);
#pragma unroll
        for (int g = 0; g < 2; ++g)
#pragma unroll
          for (int s2 = 0; s2 < 2; ++s2) {
            const int s = nt * 2 + s2;
            bf16x8 vf = *(const bf16x8*)(VtP + (g * 32 + ln) * 72 + s * 16 + hh * 8);
            union { unsigned u[4]; bf16x8 v; } pf;
            pf.u[0] = pk[s2 * 4 + 0]; pf.u[1] = pk[s2 * 4 + 1];
            pf.u[2] = pk[s2 * 4 + 2]; pf.u[3] = pk[s2 * 4 + 3];
            oa[g] = __builtin_amdgcn_mfma_f32_32x32x16_bf16(vf, pf.v, oa[g], 0, 0, 0);
          }
        __builtin_amdgcn_s_setprio(0);
      }
    }
    __syncthreads();                         // protect single-buffered LDS against next iter's writes
    ++jt;
    active = active && (jt < jt_end);
  }
  float lsum = (lsv[0] + lsv[1]) + (lsv[2] + lsv[3]);
  // ---- cross-pair merge via LDS: pair1 publishes partial O^T + partial l; pair0 sums & stores ----
  // stride 33 floats: lane t, word j -> bank (t+j)%32, lanes t and t+32 alias 2-way (free).
  float* red = (float*)Ks;                   // reuse staging LDS (last loop barrier protects it)
  if (p == 1) {
    float* dst = red + ptid * 33;
#pragma unroll
    for (int g = 0; g < 2; ++g)
#pragma unroll
      for (int r = 0; r < 16; ++r) dst[g * 16 + r] = oa[g][r];
    dst[32] = lsum;
  }
  __syncthreads();
  if (p == 0) {
    const float* src = red + ptid * 33;
#pragma unroll
    for (int g = 0; g < 2; ++g)
#pragma unroll
      for (int r = 0; r < 16; ++r) oa[g][r] += src[g * 16 + r];
    lsum += src[32];
    // l total for this lane's q: own half-wave + partner half-wave
    lsum += __shfl_xor(lsum, 32, 64);
    const float inv = 1.0f / lsum;
    // O^T epilogue: lane ln owns q-row qrow0+ln; d = colH + g*32 + (r&3)+8*(r>>2)+4*hh
#pragma unroll
    for (int g = 0; g < 2; ++g)
#pragma unroll
      for (int rg = 0; rg < 4; ++rg) {
        u16x4 ov;
#pragma unroll
        for (int i2 = 0; i2 < 4; ++i2) ov[i2] = f2bf(oa[g][rg * 4 + i2] * inv);
        *(u16x4*)(O + (size_t)(qrow0 + ln) * CD + colH + g * 32 + 8 * rg + 4 * hh) = ov;
      }
  }
}

extern "C" void kernel_launch(void* const* d_in, const int* in_sizes, int n_in,
                              void* d_out, int out_size, void* d_ws, size_t ws_size,
                              hipStream_t stream) {
  const float* x  = (const float*)d_in[0];
  const float* Wq = (const float*)d_in[1];
  const float* bq = (const float*)d_in[2];
  const float* Wk = (const float*)d_in[3];
  const float* bk = (const float*)d_in[4];
  const float* Wv = (const float*)d_in[5];
  const float* bv = (const float*)d_in[6];
  const float* Wp = (const float*)d_in[7];
  const float* bp = (const float*)d_in[8];

  char* ws = (char*)d_ws;
  u16* xb  = (u16*)(ws);                        // 8 MiB : x bf16
  u16* Wb  = (u16*)(ws + (8u << 20));           // 6 MiB : Wq,Wk,Wv bf16
  u16* Wpb = (u16*)(ws + (14u << 20));          // 2 MiB : Wp bf16
  u16* Qb  = (u16*)(ws + (16u << 20));          // 8 MiB : Q (pre-scaled by C^-0.5*log2e)
  u16* Kb  = (u16*)(ws + (24u << 20));          // 8 MiB
  u16* VTb = (u16*)(ws + (32u << 20));          // 8 MiB : V transposed [1024][4096]
  u16* Ab  = (u16*)(ws + (40u << 20));          // 8 MiB : attention output bf16

  cvt_all<<<4096, 256, 0, stream>>>(x, Wq, Wk, Wv, Wp, xb, Wb, Wpb);
  gemm_qkv<<<dim3(CD / 128, SEQ / 128, 3), 256, 0, stream>>>(xb, Wb, bq, bk, bv, Qb, Kb, VTb);
  attn_kernel<<<(SEQ / 64) * NH, 256, 0, stream>>>(Qb, Kb, VTb, Ab);
  gemm_proj<<<dim3(CD / 128, SEQ / 128), 256, 0, stream>>>(Ab, Wpb, bp, (float*)d_out);
}

// Round 13
// 199.515 us; speedup vs baseline: 1.0157x; 1.0157x over previous
//
#include <hip/hip_runtime.h>
#include <stdint.h>

typedef unsigned short u16;
typedef __bf16 bf16x8 __attribute__((ext_vector_type(8)));
typedef u16 u16x8 __attribute__((ext_vector_type(8)));
typedef u16 u16x4 __attribute__((ext_vector_type(4)));
typedef float f32x4 __attribute__((ext_vector_type(4)));
typedef float f32x16 __attribute__((ext_vector_type(16)));

#define SEQ 4096
#define CD 1024
#define NH 16
#define DHD 64

__device__ __forceinline__ u16 f2bf(float f) {
  union { float f; unsigned u; } v; v.f = f;
  unsigned r = v.u + 0x7fffu + ((v.u >> 16) & 1u);
  return (u16)(r >> 16);
}
__device__ __forceinline__ unsigned fbits(float f) {
  union { float f; unsigned u; } v; v.f = f; return v.u;
}
__device__ __forceinline__ float fexp2(float x) {
#if __has_builtin(__builtin_amdgcn_exp2f)
  return __builtin_amdgcn_exp2f(x);
#else
  return exp2f(x);
#endif
}

__device__ __forceinline__ void load_lds16(const u16* g, u16* l) {
  __builtin_amdgcn_global_load_lds((const __attribute__((address_space(1))) void*)g,
                                   (__attribute__((address_space(3))) void*)l, 16, 0, 0);
}

// ---------------- convert fp32 -> bf16 (single dispatch) ----------------
__global__ __launch_bounds__(256) void cvt_all(const float* __restrict__ x, const float* __restrict__ Wq,
                                               const float* __restrict__ Wk, const float* __restrict__ Wv,
                                               const float* __restrict__ Wp,
                                               u16* __restrict__ xb, u16* __restrict__ Wb, u16* __restrict__ Wpb) {
  int b = blockIdx.x;
  const float* src; u16* dst; int base;
  if (b < 2048)      { src = x;  dst = xb;             base = b; }
  else if (b < 2560) { src = Wq; dst = Wb;             base = b - 2048; }
  else if (b < 3072) { src = Wk; dst = Wb + CD * CD;   base = b - 2560; }
  else if (b < 3584) { src = Wv; dst = Wb + 2*CD*CD;   base = b - 3072; }
  else               { src = Wp; dst = Wpb;            base = b - 3584; }
  int i = (base * 256 + (int)threadIdx.x) * 8;
  float4 a = *(const float4*)(src + i);
  float4 c = *(const float4*)(src + i + 4);
  u16x8 o;
  o[0] = f2bf(a.x); o[1] = f2bf(a.y); o[2] = f2bf(a.z); o[3] = f2bf(a.w);
  o[4] = f2bf(c.x); o[5] = f2bf(c.y); o[6] = f2bf(c.z); o[7] = f2bf(c.w);
  *(u16x8*)(dst + i) = o;
}

// ---------------- GEMM: out = (A * Bw^T + bias) * oscale ----------------
// ROUND-2 VERSION — proven best across 4 falsified alternatives (BN=64, BM=64,
// BK=64+swizzle, LDS dbuf: all +9-15us). Do not touch.
// MODE 0: bf16 row-major; MODE 1: bf16 transposed [1024,4096]; MODE 2: f32 row-major
template<int MODE>
__device__ __forceinline__ void gemm_core(const u16* __restrict__ A, const u16* __restrict__ Bw,
                                          const float* __restrict__ bias, void* __restrict__ outp,
                                          float oscale) {
  constexpr int K = CD, N = CD;
  __shared__ u16 As[128 * 32];
  __shared__ u16 Bs[128 * 32];
  const int tid = threadIdx.x;
  const int w = tid >> 6, L = tid & 63, q = L >> 4, ln = L & 15;
  const int rowA0 = blockIdx.y * 128, rowB0 = blockIdx.x * 128;
  const int wr = (w >> 1) * 64, wc = (w & 1) * 64;
  f32x4 acc[4][4] = {};
  for (int k0 = 0; k0 < K; k0 += 32) {
#pragma unroll
    for (int pass = 0; pass < 2; ++pass) {
      int off = pass * 4096 + tid * 16;
      int row = off >> 6;
      int cole = (off & 63) >> 1;
      load_lds16(A + (size_t)(rowA0 + row) * K + k0 + cole, As + pass * 2048 + w * 512);
      load_lds16(Bw + (size_t)(rowB0 + row) * K + k0 + cole, Bs + pass * 2048 + w * 512);
    }
    __syncthreads();
    bf16x8 af[4], bg[4];
#pragma unroll
    for (int i = 0; i < 4; ++i) af[i] = *(const bf16x8*)(As + (wr + i * 16 + ln) * 32 + q * 8);
#pragma unroll
    for (int i = 0; i < 4; ++i) bg[i] = *(const bf16x8*)(Bs + (wc + i * 16 + ln) * 32 + q * 8);
#pragma unroll
    for (int i = 0; i < 4; ++i)
#pragma unroll
      for (int j = 0; j < 4; ++j)
        acc[i][j] = __builtin_amdgcn_mfma_f32_16x16x32_bf16(af[i], bg[j], acc[i][j], 0, 0, 0);
    __syncthreads();
  }
#pragma unroll
  for (int i = 0; i < 4; ++i) {
#pragma unroll
    for (int j = 0; j < 4; ++j) {
      int col = rowB0 + wc + j * 16 + ln;
      float bb = bias[col];
#pragma unroll
      for (int r = 0; r < 4; ++r) {
        int row = rowA0 + wr + i * 16 + q * 4 + r;
        float v = (acc[i][j][r] + bb) * oscale;
        if (MODE == 0)      ((u16*)outp)[(size_t)row * N + col] = f2bf(v);
        else if (MODE == 1) ((u16*)outp)[(size_t)col * SEQ + row] = f2bf(v);
        else                ((float*)outp)[(size_t)row * N + col] = v;
      }
    }
  }
}

__global__ __launch_bounds__(256) void gemm_qkv(const u16* __restrict__ A, const u16* __restrict__ W3,
                                                const float* __restrict__ bq, const float* __restrict__ bk,
                                                const float* __restrict__ bv, u16* __restrict__ Qb,
                                                u16* __restrict__ Kb, u16* __restrict__ VTb) {
  int z = blockIdx.z;
  // Q scale = C^-0.5 * log2(e): softmax scale AND exp->exp2 conversion folded into Q
  if (z == 0)      gemm_core<0>(A, W3,               bq, Qb,  0.0450842200f);
  else if (z == 1) gemm_core<0>(A, W3 + CD * CD,     bk, Kb,  1.0f);
  else             gemm_core<1>(A, W3 + 2 * CD * CD, bv, VTb, 1.0f);      // V stored transposed
}

__global__ __launch_bounds__(256) void gemm_proj(const u16* __restrict__ A, const u16* __restrict__ Bw,
                                                 const float* __restrict__ bias, float* __restrict__ out) {
  gemm_core<2>(A, Bw, bias, out, 1.0f);
}

// ---------------- flash attention (causal), 64 q-rows/block, 4 waves, in-block key-split ----------------
// ROUND-9 body with ROUND-13 change: DUAL-CHAIN MFMA INTERLEAVING (no structural change).
// R11 diagnosed the stall as the intra-wave serial chain: QK = 4 accumulator-chained MFMAs
// (~70 exposed cycles of dep latency), then exp2/pack (MFMA idle), then PV with g-outer
// order = another back-to-back dependent chain on oa[0]. At 3 waves/SIMD (register-capped,
// R8/R10) TLP cannot cover this. Fix:
//  (a) QK for BOTH nt-halves in one interleaved loop — chains aa[0]/aa[1] are independent,
//      each MFMA's result latency hides under the other chain's issue. Cost +16 VGPR
//      (both f32x16 accumulators live; est total ~160 < 170 cap at (256,3)).
//  (b) PV loop order s2-outer/g-inner — MFMAs alternate oa[0]/oa[1] chains. Free.
// aa[nt] only ever indexed by the UNROLLED nt (compile-time constant) — rule #20 safe.
// Abort signature: VGPR drop + WRITE_SIZE balloon = spill -> revert to round-9.
// All session-verified constraints retained: (256,3) final; V-in-LDS load-bearing;
// balanced per-CU qt map; Q pre-scaled by C^-0.5*log2(e) -> native exp2; no running max.
__global__ __launch_bounds__(256, 3) void attn_kernel(const u16* __restrict__ Q, const u16* __restrict__ Kg,
                                                      const u16* __restrict__ VTg, u16* __restrict__ O) {
  __shared__ u16 Ks[2][64 * 72];   // [pair]
  __shared__ u16 Vt[2][64 * 72];
  const int tid = threadIdx.x, w = tid >> 6, L = tid & 63;
  const int ln = L & 31, hh = L >> 5;
  const int p = w >> 1, sub = w & 1;         // pair = key-half, sub = q-subtile
  const int b = blockIdx.x;
  // balanced block->qt map (round-9): every CU's four blocks sum to 126 work units
  const int t4 = (b >> 4) & 15, kq = b >> 8;
  const int qt = (kq == 0) ? t4 : (kq == 1) ? 63 - t4 : (kq == 2) ? 31 - t4 : 32 + t4;
  const int h = b & 15;
  const int colH = h * DHD;
  const int qrow0 = qt * 64 + sub * 32;
  const int nt0 = (qt + 2) >> 1;             // pair0 tiles [0,nt0), pair1 [nt0, qt+1)
  int jt = p ? nt0 : 0;
  const int jt_end = p ? (qt + 1) : nt0;
  // Q B-frags (k = kk*16 + hh*8 + j over d=0..63), hoisted
  bf16x8 qf[4];
#pragma unroll
  for (int kk = 0; kk < 4; ++kk)
    qf[kk] = *(const bf16x8*)(Q + (size_t)(qrow0 + ln) * CD + colH + kk * 16 + hh * 8);
  f32x16 oa[2] = {};
  f32x4 lsv = {};                            // 4-way split lsum: breaks the 32-deep dependent add chain
  // staging map (pair-local 128 threads): c-th chunk -> row c*16 + (ptid>>3), x = ptid&7
  const int ptid = tid & 127;
  const int srow = ptid >> 3, sx = ptid & 7;
  u16* KsP = Ks[p];
  u16* VtP = Vt[p];
  u16x8 kr[4], vr[4];
  bool active = jt < jt_end;                 // pair1 empty only when qt==0
  if (active) {
#pragma unroll
    for (int c = 0; c < 4; ++c) {
      kr[c] = *(const u16x8*)(Kg + (size_t)(jt * 64 + c * 16 + srow) * CD + colH + sx * 8);
      vr[c] = *(const u16x8*)(VTg + (size_t)(colH + c * 16 + srow) * SEQ + jt * 64 + sx * 8);
    }
  }
  for (int i = 0; i < nt0; ++i) {            // nt0 is block-uniform -> barriers are safe
    if (active) {
#pragma unroll
      for (int c = 0; c < 4; ++c) {
        *(u16x8*)(KsP + (c * 16 + srow) * 72 + sx * 8) = kr[c];
        *(u16x8*)(VtP + (c * 16 + srow) * 72 + sx * 8) = vr[c];
      }
    }
    __syncthreads();
    const bool hasnext = (jt + 1) < jt_end;
    if (hasnext) {                           // prefetch next tile; latency hidden behind compute
      const size_t kb2 = (size_t)(jt + 1) * 64;
#pragma unroll
      for (int c = 0; c < 4; ++c) {
        kr[c] = *(const u16x8*)(Kg + (kb2 + c * 16 + srow) * CD + colH + sx * 8);
        vr[c] = *(const u16x8*)(VTg + (size_t)(colH + c * 16 + srow) * SEQ + kb2 + sx * 8);
      }
    }
    if (active) {
      const bool diag = (jt == qt);
      // ---- QK for BOTH halves, dual-chain interleaved: aa[0]/aa[1] independent ----
      f32x16 aa[2] = {};
      __builtin_amdgcn_s_setprio(1);
#pragma unroll
      for (int kk = 0; kk < 4; ++kk) {
        bf16x8 kf0 = *(const bf16x8*)(KsP + (ln) * 72 + kk * 16 + hh * 8);
        bf16x8 kf1 = *(const bf16x8*)(KsP + (32 + ln) * 72 + kk * 16 + hh * 8);
        aa[0] = __builtin_amdgcn_mfma_f32_32x32x16_bf16(kf0, qf[kk], aa[0], 0, 0, 0);
        aa[1] = __builtin_amdgcn_mfma_f32_32x32x16_bf16(kf1, qf[kk], aa[1], 0, 0, 0);
      }
      __builtin_amdgcn_s_setprio(0);
      // ---- per nt-half: mask, exp2, pack, swap, PV (pk live only 8 regs) ----
#pragma unroll
      for (int nt = 0; nt < 2; ++nt) {       // nt is compile-time after unroll: aa[nt] static
#pragma unroll
        for (int r = 0; r < 16; ++r) {
          float sv = aa[nt][r];
          if (diag) {
            const int key_l = nt * 32 + (r & 3) + 8 * (r >> 2) + 4 * hh;
            if (key_l > sub * 32 + ln) sv = -1e30f;
          }
          float pe = fexp2(sv);
          lsv[r & 3] += pe;
          aa[nt][r] = pe;
        }
        // pack fp32 pairs -> bf16 (truncation): pk holds keys (2i, 2i+1) of this lane's set
        unsigned pk[8];
#pragma unroll
        for (int i2 = 0; i2 < 8; ++i2)
          pk[i2] = __builtin_amdgcn_perm(fbits(aa[nt][2 * i2 + 1]), fbits(aa[nt][2 * i2]), 0x07060302);
        // exchange complementary key quads across half-wave: builds PV B-frags in-place
#pragma unroll
        for (int b0 = 0; b0 < 8; b0 += 4) {
          asm("v_permlane32_swap_b32 %0, %1" : "+v"(pk[b0 + 0]), "+v"(pk[b0 + 2]));
          asm("v_permlane32_swap_b32 %0, %1" : "+v"(pk[b0 + 1]), "+v"(pk[b0 + 3]));
        }
        // O^T += V^T P^T — s2 OUTER / g INNER so MFMAs alternate the oa[0]/oa[1] chains
        __builtin_amdgcn_s_setprio(1);
#pragma unroll
        for (int s2 = 0; s2 < 2; ++s2) {
          const int s = nt * 2 + s2;
          union { unsigned u[4]; bf16x8 v; } pf;
          pf.u[0] = pk[s2 * 4 + 0]; pf.u[1] = pk[s2 * 4 + 1];
          pf.u[2] = pk[s2 * 4 + 2]; pf.u[3] = pk[s2 * 4 + 3];
#pragma unroll
          for (int g = 0; g < 2; ++g) {
            bf16x8 vf = *(const bf16x8*)(VtP + (g * 32 + ln) * 72 + s * 16 + hh * 8);
            oa[g] = __builtin_amdgcn_mfma_f32_32x32x16_bf16(vf, pf.v, oa[g], 0, 0, 0);
          }
        }
        __builtin_amdgcn_s_setprio(0);
      }
    }
    __syncthreads();                         // protect single-buffered LDS against next iter's writes
    ++jt;
    active = active && (jt < jt_end);
  }
  float lsum = (lsv[0] + lsv[1]) + (lsv[2] + lsv[3]);
  // ---- cross-pair merge via LDS: pair1 publishes partial O^T + partial l; pair0 sums & stores ----
  // stride 33 floats: lane t, word j -> bank (t+j)%32, lanes t and t+32 alias 2-way (free).
  float* red = (float*)Ks;                   // reuse staging LDS (last loop barrier protects it)
  if (p == 1) {
    float* dst = red + ptid * 33;
#pragma unroll
    for (int g = 0; g < 2; ++g)
#pragma unroll
      for (int r = 0; r < 16; ++r) dst[g * 16 + r] = oa[g][r];
    dst[32] = lsum;
  }
  __syncthreads();
  if (p == 0) {
    const float* src = red + ptid * 33;
#pragma unroll
    for (int g = 0; g < 2; ++g)
#pragma unroll
      for (int r = 0; r < 16; ++r) oa[g][r] += src[g * 16 + r];
    lsum += src[32];
    // l total for this lane's q: own half-wave + partner half-wave
    lsum += __shfl_xor(lsum, 32, 64);
    const float inv = 1.0f / lsum;
    // O^T epilogue: lane ln owns q-row qrow0+ln; d = colH + g*32 + (r&3)+8*(r>>2)+4*hh
#pragma unroll
    for (int g = 0; g < 2; ++g)
#pragma unroll
      for (int rg = 0; rg < 4; ++rg) {
        u16x4 ov;
#pragma unroll
        for (int i2 = 0; i2 < 4; ++i2) ov[i2] = f2bf(oa[g][rg * 4 + i2] * inv);
        *(u16x4*)(O + (size_t)(qrow0 + ln) * CD + colH + g * 32 + 8 * rg + 4 * hh) = ov;
      }
  }
}

extern "C" void kernel_launch(void* const* d_in, const int* in_sizes, int n_in,
                              void* d_out, int out_size, void* d_ws, size_t ws_size,
                              hipStream_t stream) {
  const float* x  = (const float*)d_in[0];
  const float* Wq = (const float*)d_in[1];
  const float* bq = (const float*)d_in[2];
  const float* Wk = (const float*)d_in[3];
  const float* bk = (const float*)d_in[4];
  const float* Wv = (const float*)d_in[5];
  const float* bv = (const float*)d_in[6];
  const float* Wp = (const float*)d_in[7];
  const float* bp = (const float*)d_in[8];

  char* ws = (char*)d_ws;
  u16* xb  = (u16*)(ws);                        // 8 MiB : x bf16
  u16* Wb  = (u16*)(ws + (8u << 20));           // 6 MiB : Wq,Wk,Wv bf16
  u16* Wpb = (u16*)(ws + (14u << 20));          // 2 MiB : Wp bf16
  u16* Qb  = (u16*)(ws + (16u << 20));          // 8 MiB : Q (pre-scaled by C^-0.5*log2e)
  u16* Kb  = (u16*)(ws + (24u << 20));          // 8 MiB
  u16* VTb = (u16*)(ws + (32u << 20));          // 8 MiB : V transposed [1024][4096]
  u16* Ab  = (u16*)(ws + (40u << 20));          // 8 MiB : attention output bf16

  cvt_all<<<4096, 256, 0, stream>>>(x, Wq, Wk, Wv, Wp, xb, Wb, Wpb);
  gemm_qkv<<<dim3(CD / 128, SEQ / 128, 3), 256, 0, stream>>>(xb, Wb, bq, bk, bv, Qb, Kb, VTb);
  attn_kernel<<<(SEQ / 64) * NH, 256, 0, stream>>>(Qb, Kb, VTb, Ab);
  gemm_proj<<<dim3(CD / 128, SEQ / 128), 256, 0, stream>>>(Ab, Wpb, bp, (float*)d_out);
}

// Round 14
// 198.423 us; speedup vs baseline: 1.0213x; 1.0055x over previous
//
#include <hip/hip_runtime.h>
#include <stdint.h>

typedef unsigned short u16;
typedef __bf16 bf16x8 __attribute__((ext_vector_type(8)));
typedef u16 u16x8 __attribute__((ext_vector_type(8)));
typedef u16 u16x4 __attribute__((ext_vector_type(4)));
typedef float f32x4 __attribute__((ext_vector_type(4)));
typedef float f32x16 __attribute__((ext_vector_type(16)));

#define SEQ 4096
#define CD 1024
#define NH 16
#define DHD 64

__device__ __forceinline__ u16 f2bf(float f) {
  union { float f; unsigned u; } v; v.f = f;
  unsigned r = v.u + 0x7fffu + ((v.u >> 16) & 1u);
  return (u16)(r >> 16);
}
__device__ __forceinline__ unsigned fbits(float f) {
  union { float f; unsigned u; } v; v.f = f; return v.u;
}
__device__ __forceinline__ float fexp2(float x) {
#if __has_builtin(__builtin_amdgcn_exp2f)
  return __builtin_amdgcn_exp2f(x);
#else
  return exp2f(x);
#endif
}

__device__ __forceinline__ void load_lds16(const u16* g, u16* l) {
  __builtin_amdgcn_global_load_lds((const __attribute__((address_space(1))) void*)g,
                                   (__attribute__((address_space(3))) void*)l, 16, 0, 0);
}

// ---------------- convert fp32 -> bf16 (single dispatch) ----------------
__global__ __launch_bounds__(256) void cvt_all(const float* __restrict__ x, const float* __restrict__ Wq,
                                               const float* __restrict__ Wk, const float* __restrict__ Wv,
                                               const float* __restrict__ Wp,
                                               u16* __restrict__ xb, u16* __restrict__ Wb, u16* __restrict__ Wpb) {
  int b = blockIdx.x;
  const float* src; u16* dst; int base;
  if (b < 2048)      { src = x;  dst = xb;             base = b; }
  else if (b < 2560) { src = Wq; dst = Wb;             base = b - 2048; }
  else if (b < 3072) { src = Wk; dst = Wb + CD * CD;   base = b - 2560; }
  else if (b < 3584) { src = Wv; dst = Wb + 2*CD*CD;   base = b - 3072; }
  else               { src = Wp; dst = Wpb;            base = b - 3584; }
  int i = (base * 256 + (int)threadIdx.x) * 8;
  float4 a = *(const float4*)(src + i);
  float4 c = *(const float4*)(src + i + 4);
  u16x8 o;
  o[0] = f2bf(a.x); o[1] = f2bf(a.y); o[2] = f2bf(a.z); o[3] = f2bf(a.w);
  o[4] = f2bf(c.x); o[5] = f2bf(c.y); o[6] = f2bf(c.z); o[7] = f2bf(c.w);
  *(u16x8*)(dst + i) = o;
}

// ---------------- GEMM: out = (A * Bw^T + bias) * oscale ----------------
// ROUND-2 VERSION — proven best across 4 falsified alternatives (BN=64, BM=64,
// BK=64+swizzle, LDS dbuf: all +9-15us). Do not touch.
// MODE 0: bf16 row-major; MODE 1: bf16 transposed [1024,4096]; MODE 2: f32 row-major
template<int MODE>
__device__ __forceinline__ void gemm_core(const u16* __restrict__ A, const u16* __restrict__ Bw,
                                          const float* __restrict__ bias, void* __restrict__ outp,
                                          float oscale) {
  constexpr int K = CD, N = CD;
  __shared__ u16 As[128 * 32];
  __shared__ u16 Bs[128 * 32];
  const int tid = threadIdx.x;
  const int w = tid >> 6, L = tid & 63, q = L >> 4, ln = L & 15;
  const int rowA0 = blockIdx.y * 128, rowB0 = blockIdx.x * 128;
  const int wr = (w >> 1) * 64, wc = (w & 1) * 64;
  f32x4 acc[4][4] = {};
  for (int k0 = 0; k0 < K; k0 += 32) {
#pragma unroll
    for (int pass = 0; pass < 2; ++pass) {
      int off = pass * 4096 + tid * 16;
      int row = off >> 6;
      int cole = (off & 63) >> 1;
      load_lds16(A + (size_t)(rowA0 + row) * K + k0 + cole, As + pass * 2048 + w * 512);
      load_lds16(Bw + (size_t)(rowB0 + row) * K + k0 + cole, Bs + pass * 2048 + w * 512);
    }
    __syncthreads();
    bf16x8 af[4], bg[4];
#pragma unroll
    for (int i = 0; i < 4; ++i) af[i] = *(const bf16x8*)(As + (wr + i * 16 + ln) * 32 + q * 8);
#pragma unroll
    for (int i = 0; i < 4; ++i) bg[i] = *(const bf16x8*)(Bs + (wc + i * 16 + ln) * 32 + q * 8);
#pragma unroll
    for (int i = 0; i < 4; ++i)
#pragma unroll
      for (int j = 0; j < 4; ++j)
        acc[i][j] = __builtin_amdgcn_mfma_f32_16x16x32_bf16(af[i], bg[j], acc[i][j], 0, 0, 0);
    __syncthreads();
  }
#pragma unroll
  for (int i = 0; i < 4; ++i) {
#pragma unroll
    for (int j = 0; j < 4; ++j) {
      int col = rowB0 + wc + j * 16 + ln;
      float bb = bias[col];
#pragma unroll
      for (int r = 0; r < 4; ++r) {
        int row = rowA0 + wr + i * 16 + q * 4 + r;
        float v = (acc[i][j][r] + bb) * oscale;
        if (MODE == 0)      ((u16*)outp)[(size_t)row * N + col] = f2bf(v);
        else if (MODE == 1) ((u16*)outp)[(size_t)col * SEQ + row] = f2bf(v);
        else                ((float*)outp)[(size_t)row * N + col] = v;
      }
    }
  }
}

__global__ __launch_bounds__(256) void gemm_qkv(const u16* __restrict__ A, const u16* __restrict__ W3,
                                                const float* __restrict__ bq, const float* __restrict__ bk,
                                                const float* __restrict__ bv, u16* __restrict__ Qb,
                                                u16* __restrict__ Kb, u16* __restrict__ VTb) {
  int z = blockIdx.z;
  // Q scale = C^-0.5 * log2(e): softmax scale AND exp->exp2 conversion folded into Q
  if (z == 0)      gemm_core<0>(A, W3,               bq, Qb,  0.0450842200f);
  else if (z == 1) gemm_core<0>(A, W3 + CD * CD,     bk, Kb,  1.0f);
  else             gemm_core<1>(A, W3 + 2 * CD * CD, bv, VTb, 1.0f);      // V stored transposed
}

__global__ __launch_bounds__(256) void gemm_proj(const u16* __restrict__ A, const u16* __restrict__ Bw,
                                                 const float* __restrict__ bias, float* __restrict__ out) {
  gemm_core<2>(A, Bw, bias, out, 1.0f);
}

// ---------------- flash attention (causal), 64 q-rows/block, 4 waves, in-block key-split ----------------
// ROUND-13 body (dual-chain QK aa[0]/aa[1], PV s2-outer/g-inner chain alternation — best
// measured 199.5us) with ROUND-14 change: ALL s_setprio REMOVED.
// Mechanism (guide T5, m190/m191): setprio pays only when co-resident waves are at DIFFERENT
// phases (independent 1-wave blocks: +7 TF). On barrier-LOCKSTEP structures it is
// null-to-negative (m190: -14 TF on 4-wave GEMM). This kernel is the lockstep case: 4 waves
// sync twice per tile, raise priority simultaneously (nothing to arbitrate), and the 8
// setprio pairs/tile cost issue slots in the hottest loop + can delay staging waves' loads.
// All session-verified constraints retained:
//  - (256,3) bound FINAL (R1/R8: live set ~144 incl AGPR acc; any 128-reg cap spills)
//  - V staging in LDS load-bearing (R4: V-from-global -26us)
//  - balanced per-CU qt map (R9: every CU's four blocks sum to 126 units)
//  - end-barrier vmcnt drain is NOT the stall (R11 null); TLP-masked latency-bound (R10)
// Q pre-scaled by C^-0.5*log2(e) -> native exp2. No running max (|S'|<~2.2, l linear).
__global__ __launch_bounds__(256, 3) void attn_kernel(const u16* __restrict__ Q, const u16* __restrict__ Kg,
                                                      const u16* __restrict__ VTg, u16* __restrict__ O) {
  __shared__ u16 Ks[2][64 * 72];   // [pair]
  __shared__ u16 Vt[2][64 * 72];
  const int tid = threadIdx.x, w = tid >> 6, L = tid & 63;
  const int ln = L & 31, hh = L >> 5;
  const int p = w >> 1, sub = w & 1;         // pair = key-half, sub = q-subtile
  const int b = blockIdx.x;
  // balanced block->qt map (round-9): every CU's four blocks sum to 126 work units
  const int t4 = (b >> 4) & 15, kq = b >> 8;
  const int qt = (kq == 0) ? t4 : (kq == 1) ? 63 - t4 : (kq == 2) ? 31 - t4 : 32 + t4;
  const int h = b & 15;
  const int colH = h * DHD;
  const int qrow0 = qt * 64 + sub * 32;
  const int nt0 = (qt + 2) >> 1;             // pair0 tiles [0,nt0), pair1 [nt0, qt+1)
  int jt = p ? nt0 : 0;
  const int jt_end = p ? (qt + 1) : nt0;
  // Q B-frags (k = kk*16 + hh*8 + j over d=0..63), hoisted
  bf16x8 qf[4];
#pragma unroll
  for (int kk = 0; kk < 4; ++kk)
    qf[kk] = *(const bf16x8*)(Q + (size_t)(qrow0 + ln) * CD + colH + kk * 16 + hh * 8);
  f32x16 oa[2] = {};
  f32x4 lsv = {};                            // 4-way split lsum: breaks the 32-deep dependent add chain
  // staging map (pair-local 128 threads): c-th chunk -> row c*16 + (ptid>>3), x = ptid&7
  const int ptid = tid & 127;
  const int srow = ptid >> 3, sx = ptid & 7;
  u16* KsP = Ks[p];
  u16* VtP = Vt[p];
  u16x8 kr[4], vr[4];
  bool active = jt < jt_end;                 // pair1 empty only when qt==0
  if (active) {
#pragma unroll
    for (int c = 0; c < 4; ++c) {
      kr[c] = *(const u16x8*)(Kg + (size_t)(jt * 64 + c * 16 + srow) * CD + colH + sx * 8);
      vr[c] = *(const u16x8*)(VTg + (size_t)(colH + c * 16 + srow) * SEQ + jt * 64 + sx * 8);
    }
  }
  for (int i = 0; i < nt0; ++i) {            // nt0 is block-uniform -> barriers are safe
    if (active) {
#pragma unroll
      for (int c = 0; c < 4; ++c) {
        *(u16x8*)(KsP + (c * 16 + srow) * 72 + sx * 8) = kr[c];
        *(u16x8*)(VtP + (c * 16 + srow) * 72 + sx * 8) = vr[c];
      }
    }
    __syncthreads();
    const bool hasnext = (jt + 1) < jt_end;
    if (hasnext) {                           // prefetch next tile; latency hidden behind compute
      const size_t kb2 = (size_t)(jt + 1) * 64;
#pragma unroll
      for (int c = 0; c < 4; ++c) {
        kr[c] = *(const u16x8*)(Kg + (kb2 + c * 16 + srow) * CD + colH + sx * 8);
        vr[c] = *(const u16x8*)(VTg + (size_t)(colH + c * 16 + srow) * SEQ + kb2 + sx * 8);
      }
    }
    if (active) {
      const bool diag = (jt == qt);
      // ---- QK for BOTH halves, dual-chain interleaved: aa[0]/aa[1] independent ----
      f32x16 aa[2] = {};
#pragma unroll
      for (int kk = 0; kk < 4; ++kk) {
        bf16x8 kf0 = *(const bf16x8*)(KsP + (ln) * 72 + kk * 16 + hh * 8);
        bf16x8 kf1 = *(const bf16x8*)(KsP + (32 + ln) * 72 + kk * 16 + hh * 8);
        aa[0] = __builtin_amdgcn_mfma_f32_32x32x16_bf16(kf0, qf[kk], aa[0], 0, 0, 0);
        aa[1] = __builtin_amdgcn_mfma_f32_32x32x16_bf16(kf1, qf[kk], aa[1], 0, 0, 0);
      }
      // ---- per nt-half: mask, exp2, pack, swap, PV (pk live only 8 regs) ----
#pragma unroll
      for (int nt = 0; nt < 2; ++nt) {       // nt is compile-time after unroll: aa[nt] static
#pragma unroll
        for (int r = 0; r < 16; ++r) {
          float sv = aa[nt][r];
          if (diag) {
            const int key_l = nt * 32 + (r & 3) + 8 * (r >> 2) + 4 * hh;
            if (key_l > sub * 32 + ln) sv = -1e30f;
          }
          float pe = fexp2(sv);
          lsv[r & 3] += pe;
          aa[nt][r] = pe;
        }
        // pack fp32 pairs -> bf16 (truncation): pk holds keys (2i, 2i+1) of this lane's set
        unsigned pk[8];
#pragma unroll
        for (int i2 = 0; i2 < 8; ++i2)
          pk[i2] = __builtin_amdgcn_perm(fbits(aa[nt][2 * i2 + 1]), fbits(aa[nt][2 * i2]), 0x07060302);
        // exchange complementary key quads across half-wave: builds PV B-frags in-place
#pragma unroll
        for (int b0 = 0; b0 < 8; b0 += 4) {
          asm("v_permlane32_swap_b32 %0, %1" : "+v"(pk[b0 + 0]), "+v"(pk[b0 + 2]));
          asm("v_permlane32_swap_b32 %0, %1" : "+v"(pk[b0 + 1]), "+v"(pk[b0 + 3]));
        }
        // O^T += V^T P^T — s2 OUTER / g INNER so MFMAs alternate the oa[0]/oa[1] chains
#pragma unroll
        for (int s2 = 0; s2 < 2; ++s2) {
          const int s = nt * 2 + s2;
          union { unsigned u[4]; bf16x8 v; } pf;
          pf.u[0] = pk[s2 * 4 + 0]; pf.u[1] = pk[s2 * 4 + 1];
          pf.u[2] = pk[s2 * 4 + 2]; pf.u[3] = pk[s2 * 4 + 3];
#pragma unroll
          for (int g = 0; g < 2; ++g) {
            bf16x8 vf = *(const bf16x8*)(VtP + (g * 32 + ln) * 72 + s * 16 + hh * 8);
            oa[g] = __builtin_amdgcn_mfma_f32_32x32x16_bf16(vf, pf.v, oa[g], 0, 0, 0);
          }
        }
      }
    }
    __syncthreads();                         // protect single-buffered LDS against next iter's writes
    ++jt;
    active = active && (jt < jt_end);
  }
  float lsum = (lsv[0] + lsv[1]) + (lsv[2] + lsv[3]);
  // ---- cross-pair merge via LDS: pair1 publishes partial O^T + partial l; pair0 sums & stores ----
  // stride 33 floats: lane t, word j -> bank (t+j)%32, lanes t and t+32 alias 2-way (free).
  float* red = (float*)Ks;                   // reuse staging LDS (last loop barrier protects it)
  if (p == 1) {
    float* dst = red + ptid * 33;
#pragma unroll
    for (int g = 0; g < 2; ++g)
#pragma unroll
      for (int r = 0; r < 16; ++r) dst[g * 16 + r] = oa[g][r];
    dst[32] = lsum;
  }
  __syncthreads();
  if (p == 0) {
    const float* src = red + ptid * 33;
#pragma unroll
    for (int g = 0; g < 2; ++g)
#pragma unroll
      for (int r = 0; r < 16; ++r) oa[g][r] += src[g * 16 + r];
    lsum += src[32];
    // l total for this lane's q: own half-wave + partner half-wave
    lsum += __shfl_xor(lsum, 32, 64);
    const float inv = 1.0f / lsum;
    // O^T epilogue: lane ln owns q-row qrow0+ln; d = colH + g*32 + (r&3)+8*(r>>2)+4*hh
#pragma unroll
    for (int g = 0; g < 2; ++g)
#pragma unroll
      for (int rg = 0; rg < 4; ++rg) {
        u16x4 ov;
#pragma unroll
        for (int i2 = 0; i2 < 4; ++i2) ov[i2] = f2bf(oa[g][rg * 4 + i2] * inv);
        *(u16x4*)(O + (size_t)(qrow0 + ln) * CD + colH + g * 32 + 8 * rg + 4 * hh) = ov;
      }
  }
}

extern "C" void kernel_launch(void* const* d_in, const int* in_sizes, int n_in,
                              void* d_out, int out_size, void* d_ws, size_t ws_size,
                              hipStream_t stream) {
  const float* x  = (const float*)d_in[0];
  const float* Wq = (const float*)d_in[1];
  const float* bq = (const float*)d_in[2];
  const float* Wk = (const float*)d_in[3];
  const float* bk = (const float*)d_in[4];
  const float* Wv = (const float*)d_in[5];
  const float* bv = (const float*)d_in[6];
  const float* Wp = (const float*)d_in[7];
  const float* bp = (const float*)d_in[8];

  char* ws = (char*)d_ws;
  u16* xb  = (u16*)(ws);                        // 8 MiB : x bf16
  u16* Wb  = (u16*)(ws + (8u << 20));           // 6 MiB : Wq,Wk,Wv bf16
  u16* Wpb = (u16*)(ws + (14u << 20));          // 2 MiB : Wp bf16
  u16* Qb  = (u16*)(ws + (16u << 20));          // 8 MiB : Q (pre-scaled by C^-0.5*log2e)
  u16* Kb  = (u16*)(ws + (24u << 20));          // 8 MiB
  u16* VTb = (u16*)(ws + (32u << 20));          // 8 MiB : V transposed [1024][4096]
  u16* Ab  = (u16*)(ws + (40u << 20));          // 8 MiB : attention output bf16

  cvt_all<<<4096, 256, 0, stream>>>(x, Wq, Wk, Wv, Wp, xb, Wb, Wpb);
  gemm_qkv<<<dim3(CD / 128, SEQ / 128, 3), 256, 0, stream>>>(xb, Wb, bq, bk, bv, Qb, Kb, VTb);
  attn_kernel<<<(SEQ / 64) * NH, 256, 0, stream>>>(Qb, Kb, VTb, Ab);
  gemm_proj<<<dim3(CD / 128, SEQ / 128), 256, 0, stream>>>(Ab, Wpb, bp, (float*)d_out);
}

// Round 15
// 198.192 us; speedup vs baseline: 1.0225x; 1.0012x over previous
//
#include <hip/hip_runtime.h>
#include <stdint.h>

typedef unsigned short u16;
typedef __bf16 bf16x8 __attribute__((ext_vector_type(8)));
typedef u16 u16x8 __attribute__((ext_vector_type(8)));
typedef u16 u16x4 __attribute__((ext_vector_type(4)));
typedef float f32x4 __attribute__((ext_vector_type(4)));
typedef float f32x16 __attribute__((ext_vector_type(16)));

#define SEQ 4096
#define CD 1024
#define NH 16
#define DHD 64

__device__ __forceinline__ u16 f2bf(float f) {
  union { float f; unsigned u; } v; v.f = f;
  unsigned r = v.u + 0x7fffu + ((v.u >> 16) & 1u);
  return (u16)(r >> 16);
}
__device__ __forceinline__ unsigned fbits(float f) {
  union { float f; unsigned u; } v; v.f = f; return v.u;
}
__device__ __forceinline__ float fexp2(float x) {
#if __has_builtin(__builtin_amdgcn_exp2f)
  return __builtin_amdgcn_exp2f(x);
#else
  return exp2f(x);
#endif
}

__device__ __forceinline__ void load_lds16(const u16* g, u16* l) {
  __builtin_amdgcn_global_load_lds((const __attribute__((address_space(1))) void*)g,
                                   (__attribute__((address_space(3))) void*)l, 16, 0, 0);
}

// ---------------- convert fp32 -> bf16 (single dispatch) ----------------
__global__ __launch_bounds__(256) void cvt_all(const float* __restrict__ x, const float* __restrict__ Wq,
                                               const float* __restrict__ Wk, const float* __restrict__ Wv,
                                               const float* __restrict__ Wp,
                                               u16* __restrict__ xb, u16* __restrict__ Wb, u16* __restrict__ Wpb) {
  int b = blockIdx.x;
  const float* src; u16* dst; int base;
  if (b < 2048)      { src = x;  dst = xb;             base = b; }
  else if (b < 2560) { src = Wq; dst = Wb;             base = b - 2048; }
  else if (b < 3072) { src = Wk; dst = Wb + CD * CD;   base = b - 2560; }
  else if (b < 3584) { src = Wv; dst = Wb + 2*CD*CD;   base = b - 3072; }
  else               { src = Wp; dst = Wpb;            base = b - 3584; }
  int i = (base * 256 + (int)threadIdx.x) * 8;
  float4 a = *(const float4*)(src + i);
  float4 c = *(const float4*)(src + i + 4);
  u16x8 o;
  o[0] = f2bf(a.x); o[1] = f2bf(a.y); o[2] = f2bf(a.z); o[3] = f2bf(a.w);
  o[4] = f2bf(c.x); o[5] = f2bf(c.y); o[6] = f2bf(c.z); o[7] = f2bf(c.w);
  *(u16x8*)(dst + i) = o;
}

// ---------------- GEMM: out = (A * Bw^T + bias) * oscale ----------------
// ROUND-2 VERSION — proven best across 4 falsified alternatives (BN=64, BM=64,
// BK=64+swizzle, LDS dbuf: all +9-15us). Do not touch.
// MODE 0: bf16 row-major; MODE 1: bf16 transposed [1024,4096]; MODE 2: f32 row-major
template<int MODE>
__device__ __forceinline__ void gemm_core(const u16* __restrict__ A, const u16* __restrict__ Bw,
                                          const float* __restrict__ bias, void* __restrict__ outp,
                                          float oscale) {
  constexpr int K = CD, N = CD;
  __shared__ u16 As[128 * 32];
  __shared__ u16 Bs[128 * 32];
  const int tid = threadIdx.x;
  const int w = tid >> 6, L = tid & 63, q = L >> 4, ln = L & 15;
  const int rowA0 = blockIdx.y * 128, rowB0 = blockIdx.x * 128;
  const int wr = (w >> 1) * 64, wc = (w & 1) * 64;
  f32x4 acc[4][4] = {};
  for (int k0 = 0; k0 < K; k0 += 32) {
#pragma unroll
    for (int pass = 0; pass < 2; ++pass) {
      int off = pass * 4096 + tid * 16;
      int row = off >> 6;
      int cole = (off & 63) >> 1;
      load_lds16(A + (size_t)(rowA0 + row) * K + k0 + cole, As + pass * 2048 + w * 512);
      load_lds16(Bw + (size_t)(rowB0 + row) * K + k0 + cole, Bs + pass * 2048 + w * 512);
    }
    __syncthreads();
    bf16x8 af[4], bg[4];
#pragma unroll
    for (int i = 0; i < 4; ++i) af[i] = *(const bf16x8*)(As + (wr + i * 16 + ln) * 32 + q * 8);
#pragma unroll
    for (int i = 0; i < 4; ++i) bg[i] = *(const bf16x8*)(Bs + (wc + i * 16 + ln) * 32 + q * 8);
#pragma unroll
    for (int i = 0; i < 4; ++i)
#pragma unroll
      for (int j = 0; j < 4; ++j)
        acc[i][j] = __builtin_amdgcn_mfma_f32_16x16x32_bf16(af[i], bg[j], acc[i][j], 0, 0, 0);
    __syncthreads();
  }
#pragma unroll
  for (int i = 0; i < 4; ++i) {
#pragma unroll
    for (int j = 0; j < 4; ++j) {
      int col = rowB0 + wc + j * 16 + ln;
      float bb = bias[col];
#pragma unroll
      for (int r = 0; r < 4; ++r) {
        int row = rowA0 + wr + i * 16 + q * 4 + r;
        float v = (acc[i][j][r] + bb) * oscale;
        if (MODE == 0)      ((u16*)outp)[(size_t)row * N + col] = f2bf(v);
        else if (MODE == 1) ((u16*)outp)[(size_t)col * SEQ + row] = f2bf(v);
        else                ((float*)outp)[(size_t)row * N + col] = v;
      }
    }
  }
}

__global__ __launch_bounds__(256) void gemm_qkv(const u16* __restrict__ A, const u16* __restrict__ W3,
                                                const float* __restrict__ bq, const float* __restrict__ bk,
                                                const float* __restrict__ bv, u16* __restrict__ Qb,
                                                u16* __restrict__ Kb, u16* __restrict__ VTb) {
  int z = blockIdx.z;
  // Q scale = C^-0.5 * log2(e): softmax scale AND exp->exp2 conversion folded into Q
  if (z == 0)      gemm_core<0>(A, W3,               bq, Qb,  0.0450842200f);
  else if (z == 1) gemm_core<0>(A, W3 + CD * CD,     bk, Kb,  1.0f);
  else             gemm_core<1>(A, W3 + 2 * CD * CD, bv, VTb, 1.0f);      // V stored transposed
}

__global__ __launch_bounds__(256) void gemm_proj(const u16* __restrict__ A, const u16* __restrict__ Bw,
                                                 const float* __restrict__ bias, float* __restrict__ out) {
  gemm_core<2>(A, Bw, bias, out, 1.0f);
}

// ---------------- flash attention (causal), 64 q-rows/block, 4 waves, in-block key-split ----------------
// ROUND-14 body (dual-chain QK, PV chain alternation, no setprio — best measured 198.4us)
// with ROUND-15 change (one line): kq groups reordered HEAVY-FIRST / LIGHT-LAST.
// Residency is 3 blk/CU (768 of 1024 co-resident) -> the last-launched kq group forms the
// straggler tail. R9's map launched lightest (qt 0-15) FIRST and medium-heavy (32-47) LAST —
// anti-LPT. New map: kq0: 63-t4 (avg 55.5), kq1: 32+t4 (39.5), kq2: 31-t4 (23.5),
// kq3: t4 (7.5). Per-t4 sum = 126 for every t4 (R9's balance invariant preserved exactly),
// bijective over 0..63, group averages descend = LPT, robust to dynamic slot refill.
// All session-verified constraints retained:
//  - (256,3) bound FINAL (R1/R8: live set ~144 incl AGPR acc; any 128-reg cap spills)
//  - V staging in LDS load-bearing (R4: V-from-global -26us)
//  - no setprio (R14: lockstep structure, T5 null-to-negative mechanism)
//  - end-barrier vmcnt drain is NOT the stall (R11 null); TLP-masked latency-bound (R10)
// Q pre-scaled by C^-0.5*log2(e) -> native exp2. No running max (|S'|<~2.2, l linear).
__global__ __launch_bounds__(256, 3) void attn_kernel(const u16* __restrict__ Q, const u16* __restrict__ Kg,
                                                      const u16* __restrict__ VTg, u16* __restrict__ O) {
  __shared__ u16 Ks[2][64 * 72];   // [pair]
  __shared__ u16 Vt[2][64 * 72];
  const int tid = threadIdx.x, w = tid >> 6, L = tid & 63;
  const int ln = L & 31, hh = L >> 5;
  const int p = w >> 1, sub = w & 1;         // pair = key-half, sub = q-subtile
  const int b = blockIdx.x;
  // balanced + LPT block->qt map (see header comment)
  const int t4 = (b >> 4) & 15, kq = b >> 8;
  const int qt = (kq == 0) ? 63 - t4 : (kq == 1) ? 32 + t4 : (kq == 2) ? 31 - t4 : t4;
  const int h = b & 15;
  const int colH = h * DHD;
  const int qrow0 = qt * 64 + sub * 32;
  const int nt0 = (qt + 2) >> 1;             // pair0 tiles [0,nt0), pair1 [nt0, qt+1)
  int jt = p ? nt0 : 0;
  const int jt_end = p ? (qt + 1) : nt0;
  // Q B-frags (k = kk*16 + hh*8 + j over d=0..63), hoisted
  bf16x8 qf[4];
#pragma unroll
  for (int kk = 0; kk < 4; ++kk)
    qf[kk] = *(const bf16x8*)(Q + (size_t)(qrow0 + ln) * CD + colH + kk * 16 + hh * 8);
  f32x16 oa[2] = {};
  f32x4 lsv = {};                            // 4-way split lsum: breaks the 32-deep dependent add chain
  // staging map (pair-local 128 threads): c-th chunk -> row c*16 + (ptid>>3), x = ptid&7
  const int ptid = tid & 127;
  const int srow = ptid >> 3, sx = ptid & 7;
  u16* KsP = Ks[p];
  u16* VtP = Vt[p];
  u16x8 kr[4], vr[4];
  bool active = jt < jt_end;                 // pair1 empty only when qt==0
  if (active) {
#pragma unroll
    for (int c = 0; c < 4; ++c) {
      kr[c] = *(const u16x8*)(Kg + (size_t)(jt * 64 + c * 16 + srow) * CD + colH + sx * 8);
      vr[c] = *(const u16x8*)(VTg + (size_t)(colH + c * 16 + srow) * SEQ + jt * 64 + sx * 8);
    }
  }
  for (int i = 0; i < nt0; ++i) {            // nt0 is block-uniform -> barriers are safe
    if (active) {
#pragma unroll
      for (int c = 0; c < 4; ++c) {
        *(u16x8*)(KsP + (c * 16 + srow) * 72 + sx * 8) = kr[c];
        *(u16x8*)(VtP + (c * 16 + srow) * 72 + sx * 8) = vr[c];
      }
    }
    __syncthreads();
    const bool hasnext = (jt + 1) < jt_end;
    if (hasnext) {                           // prefetch next tile; latency hidden behind compute
      const size_t kb2 = (size_t)(jt + 1) * 64;
#pragma unroll
      for (int c = 0; c < 4; ++c) {
        kr[c] = *(const u16x8*)(Kg + (kb2 + c * 16 + srow) * CD + colH + sx * 8);
        vr[c] = *(const u16x8*)(VTg + (size_t)(colH + c * 16 + srow) * SEQ + kb2 + sx * 8);
      }
    }
    if (active) {
      const bool diag = (jt == qt);
      // ---- QK for BOTH halves, dual-chain interleaved: aa[0]/aa[1] independent ----
      f32x16 aa[2] = {};
#pragma unroll
      for (int kk = 0; kk < 4; ++kk) {
        bf16x8 kf0 = *(const bf16x8*)(KsP + (ln) * 72 + kk * 16 + hh * 8);
        bf16x8 kf1 = *(const bf16x8*)(KsP + (32 + ln) * 72 + kk * 16 + hh * 8);
        aa[0] = __builtin_amdgcn_mfma_f32_32x32x16_bf16(kf0, qf[kk], aa[0], 0, 0, 0);
        aa[1] = __builtin_amdgcn_mfma_f32_32x32x16_bf16(kf1, qf[kk], aa[1], 0, 0, 0);
      }
      // ---- per nt-half: mask, exp2, pack, swap, PV (pk live only 8 regs) ----
#pragma unroll
      for (int nt = 0; nt < 2; ++nt) {       // nt is compile-time after unroll: aa[nt] static
#pragma unroll
        for (int r = 0; r < 16; ++r) {
          float sv = aa[nt][r];
          if (diag) {
            const int key_l = nt * 32 + (r & 3) + 8 * (r >> 2) + 4 * hh;
            if (key_l > sub * 32 + ln) sv = -1e30f;
          }
          float pe = fexp2(sv);
          lsv[r & 3] += pe;
          aa[nt][r] = pe;
        }
        // pack fp32 pairs -> bf16 (truncation): pk holds keys (2i, 2i+1) of this lane's set
        unsigned pk[8];
#pragma unroll
        for (int i2 = 0; i2 < 8; ++i2)
          pk[i2] = __builtin_amdgcn_perm(fbits(aa[nt][2 * i2 + 1]), fbits(aa[nt][2 * i2]), 0x07060302);
        // exchange complementary key quads across half-wave: builds PV B-frags in-place
#pragma unroll
        for (int b0 = 0; b0 < 8; b0 += 4) {
          asm("v_permlane32_swap_b32 %0, %1" : "+v"(pk[b0 + 0]), "+v"(pk[b0 + 2]));
          asm("v_permlane32_swap_b32 %0, %1" : "+v"(pk[b0 + 1]), "+v"(pk[b0 + 3]));
        }
        // O^T += V^T P^T — s2 OUTER / g INNER so MFMAs alternate the oa[0]/oa[1] chains
#pragma unroll
        for (int s2 = 0; s2 < 2; ++s2) {
          const int s = nt * 2 + s2;
          union { unsigned u[4]; bf16x8 v; } pf;
          pf.u[0] = pk[s2 * 4 + 0]; pf.u[1] = pk[s2 * 4 + 1];
          pf.u[2] = pk[s2 * 4 + 2]; pf.u[3] = pk[s2 * 4 + 3];
#pragma unroll
          for (int g = 0; g < 2; ++g) {
            bf16x8 vf = *(const bf16x8*)(VtP + (g * 32 + ln) * 72 + s * 16 + hh * 8);
            oa[g] = __builtin_amdgcn_mfma_f32_32x32x16_bf16(vf, pf.v, oa[g], 0, 0, 0);
          }
        }
      }
    }
    __syncthreads();                         // protect single-buffered LDS against next iter's writes
    ++jt;
    active = active && (jt < jt_end);
  }
  float lsum = (lsv[0] + lsv[1]) + (lsv[2] + lsv[3]);
  // ---- cross-pair merge via LDS: pair1 publishes partial O^T + partial l; pair0 sums & stores ----
  // stride 33 floats: lane t, word j -> bank (t+j)%32, lanes t and t+32 alias 2-way (free).
  float* red = (float*)Ks;                   // reuse staging LDS (last loop barrier protects it)
  if (p == 1) {
    float* dst = red + ptid * 33;
#pragma unroll
    for (int g = 0; g < 2; ++g)
#pragma unroll
      for (int r = 0; r < 16; ++r) dst[g * 16 + r] = oa[g][r];
    dst[32] = lsum;
  }
  __syncthreads();
  if (p == 0) {
    const float* src = red + ptid * 33;
#pragma unroll
    for (int g = 0; g < 2; ++g)
#pragma unroll
      for (int r = 0; r < 16; ++r) oa[g][r] += src[g * 16 + r];
    lsum += src[32];
    // l total for this lane's q: own half-wave + partner half-wave
    lsum += __shfl_xor(lsum, 32, 64);
    const float inv = 1.0f / lsum;
    // O^T epilogue: lane ln owns q-row qrow0+ln; d = colH + g*32 + (r&3)+8*(r>>2)+4*hh
#pragma unroll
    for (int g = 0; g < 2; ++g)
#pragma unroll
      for (int rg = 0; rg < 4; ++rg) {
        u16x4 ov;
#pragma unroll
        for (int i2 = 0; i2 < 4; ++i2) ov[i2] = f2bf(oa[g][rg * 4 + i2] * inv);
        *(u16x4*)(O + (size_t)(qrow0 + ln) * CD + colH + g * 32 + 8 * rg + 4 * hh) = ov;
      }
  }
}

extern "C" void kernel_launch(void* const* d_in, const int* in_sizes, int n_in,
                              void* d_out, int out_size, void* d_ws, size_t ws_size,
                              hipStream_t stream) {
  const float* x  = (const float*)d_in[0];
  const float* Wq = (const float*)d_in[1];
  const float* bq = (const float*)d_in[2];
  const float* Wk = (const float*)d_in[3];
  const float* bk = (const float*)d_in[4];
  const float* Wv = (const float*)d_in[5];
  const float* bv = (const float*)d_in[6];
  const float* Wp = (const float*)d_in[7];
  const float* bp = (const float*)d_in[8];

  char* ws = (char*)d_ws;
  u16* xb  = (u16*)(ws);                        // 8 MiB : x bf16
  u16* Wb  = (u16*)(ws + (8u << 20));           // 6 MiB : Wq,Wk,Wv bf16
  u16* Wpb = (u16*)(ws + (14u << 20));          // 2 MiB : Wp bf16
  u16* Qb  = (u16*)(ws + (16u << 20));          // 8 MiB : Q (pre-scaled by C^-0.5*log2e)
  u16* Kb  = (u16*)(ws + (24u << 20));          // 8 MiB
  u16* VTb = (u16*)(ws + (32u << 20));          // 8 MiB : V transposed [1024][4096]
  u16* Ab  = (u16*)(ws + (40u << 20));          // 8 MiB : attention output bf16

  cvt_all<<<4096, 256, 0, stream>>>(x, Wq, Wk, Wv, Wp, xb, Wb, Wpb);
  gemm_qkv<<<dim3(CD / 128, SEQ / 128, 3), 256, 0, stream>>>(xb, Wb, bq, bk, bv, Qb, Kb, VTb);
  attn_kernel<<<(SEQ / 64) * NH, 256, 0, stream>>>(Qb, Kb, VTb, Ab);
  gemm_proj<<<dim3(CD / 128, SEQ / 128), 256, 0, stream>>>(Ab, Wpb, bp, (float*)d_out);
}